// Round 1
// baseline (212.153 us; speedup 1.0000x reference)
//
#include <hip/hip_runtime.h>

// ---------------------------------------------------------------------------
// R_SCNN: two width-direction SCNN scans (fused into one 127-step sweep),
// channel-dot (1x1 conv) folded INTO the scan, then 4x bilinear upsample of
// the resulting scalar field + global BN + sigmoid.
//
//   y_w = c_w + relu(M y_{w-1}),  z_w = y_w + relu(M z_{w-1}),  z_0 = y_0 = c_0
//   s[b,h,wo] = dot(v, z_{127-wo});  out = sigmoid(BN(upsample4(s)))
//
// 128 columns (b,h) -> 128 independent workgroups; M lives in registers as
// f16 pairs, inner product via v_dot2_f32_f16.
// ---------------------------------------------------------------------------

typedef _Float16 h2 __attribute__((ext_vector_type(2)));

static __device__ __forceinline__ float fdot2(h2 a, h2 b, float c) {
#if __has_builtin(__builtin_amdgcn_fdot2)
  return __builtin_amdgcn_fdot2(a, b, c, false);
#else
  return c + (float)a.x * (float)b.x + (float)a.y * (float)b.y;
#endif
}

// ---- kernel 0: extract center tap of conv_w into dense f16 [o][c] ----------
extern "C" __global__ void k_extract(const float* __restrict__ convw,
                                     _Float16* __restrict__ Md) {
  int idx = blockIdx.x * 256 + threadIdx.x;      // 65536 = 256 x 256
  Md[idx] = (_Float16)convw[idx * 9 + 4];        // conv_w[o][c][0][4], stride 9
}

// ---- kernel 1: fused double scan + channel dot -----------------------------
struct SM1 {
  _Float16 cy[256] __attribute__((aligned(16)));  // y carry (f16)
  _Float16 cz[256] __attribute__((aligned(16)));  // z carry (f16)
  float    py[8 * 256];                           // y partials [r][o]
  float    pz[8 * 256];                           // z partials [r][o]
  float    sp[128 * 4];                           // s partial dots [w][wave]
};

extern "C" __global__ void __launch_bounds__(512, 2)
k_scan(const float* __restrict__ p2, const _Float16* __restrict__ Md,
       const float* __restrict__ conv1, float* __restrict__ sout,
       float* __restrict__ stats) {
  __shared__ SM1 sm;
  const int tid  = threadIdx.x;
  const int lane = tid & 63;
  const int r    = tid >> 6;          // wave id 0..7 (= k-chunk in phase A)
  const int b    = blockIdx.x >> 6;
  const int h    = blockIdx.x & 63;

  if (blockIdx.x == 0 && tid == 0) { stats[0] = 0.f; stats[1] = 0.f; }

  // M fragment in registers: rows o = lane*4+i, cols r*32 .. r*32+31 (f16 pairs)
  h2 M[4][16];
#pragma unroll
  for (int i = 0; i < 4; ++i) {
    const uint4* mp = (const uint4*)(Md + ((lane * 4 + i) * 256 + r * 32));
#pragma unroll
    for (int j = 0; j < 4; ++j) {
      uint4 d = mp[j];
      M[i][j * 4 + 0] = __builtin_bit_cast(h2, d.x);
      M[i][j * 4 + 1] = __builtin_bit_cast(h2, d.y);
      M[i][j * 4 + 2] = __builtin_bit_cast(h2, d.z);
      M[i][j * 4 + 3] = __builtin_bit_cast(h2, d.w);
    }
  }

  // p2_r[b][o][h][w] : element o at +o*8192, w contiguous
  const float* pbase = p2 + (((size_t)b * 256) * 64 + h) * 128;

  float vreg = 0.f, cnext = 0.f;
  if (tid < 256) {
    vreg = conv1[tid];
    float c0 = pbase[(size_t)tid * 8192 + 0];
    cnext    = pbase[(size_t)tid * 8192 + 1];   // prefetch c for w=1
    sm.cy[tid] = (_Float16)c0;
    sm.cz[tid] = (_Float16)c0;
    // s contribution for w=0 (z_0 = c_0)
    float val = vreg * c0;
#pragma unroll
    for (int off = 32; off > 0; off >>= 1) val += __shfl_xor(val, off, 64);
    if (lane == 0) sm.sp[0 * 4 + r] = val;
  }
  __syncthreads();

  const uint4* cy4 = (const uint4*)sm.cy + r * 4;   // this wave's 32-f16 chunk
  const uint4* cz4 = (const uint4*)sm.cz + r * 4;
  float4* pyw = (float4*)(sm.py + r * 256 + lane * 4);
  float4* pzw = (float4*)(sm.pz + r * 256 + lane * 4);

  for (int w = 1; w < 128; ++w) {
    // ---------------- phase A: partial dot products (all 512 threads) ------
    uint4 Y[4], Z[4];
#pragma unroll
    for (int j = 0; j < 4; ++j) { Y[j] = cy4[j]; Z[j] = cz4[j]; }
    h2 yv[16], zv[16];
#pragma unroll
    for (int j = 0; j < 4; ++j) {
      yv[j * 4 + 0] = __builtin_bit_cast(h2, Y[j].x);
      yv[j * 4 + 1] = __builtin_bit_cast(h2, Y[j].y);
      yv[j * 4 + 2] = __builtin_bit_cast(h2, Y[j].z);
      yv[j * 4 + 3] = __builtin_bit_cast(h2, Y[j].w);
      zv[j * 4 + 0] = __builtin_bit_cast(h2, Z[j].x);
      zv[j * 4 + 1] = __builtin_bit_cast(h2, Z[j].y);
      zv[j * 4 + 2] = __builtin_bit_cast(h2, Z[j].z);
      zv[j * 4 + 3] = __builtin_bit_cast(h2, Z[j].w);
    }
    float ay0 = 0.f, ay1 = 0.f, ay2 = 0.f, ay3 = 0.f;
    float az0 = 0.f, az1 = 0.f, az2 = 0.f, az3 = 0.f;
#pragma unroll
    for (int k = 0; k < 16; ++k) {
      ay0 = fdot2(M[0][k], yv[k], ay0);
      ay1 = fdot2(M[1][k], yv[k], ay1);
      ay2 = fdot2(M[2][k], yv[k], ay2);
      ay3 = fdot2(M[3][k], yv[k], ay3);
      az0 = fdot2(M[0][k], zv[k], az0);
      az1 = fdot2(M[1][k], zv[k], az1);
      az2 = fdot2(M[2][k], zv[k], az2);
      az3 = fdot2(M[3][k], zv[k], az3);
    }
    *pyw = make_float4(ay0, ay1, ay2, ay3);
    *pzw = make_float4(az0, az1, az2, az3);
    __syncthreads();

    // ---------------- phase B: reduce + carry update (256 threads) ---------
    if (tid < 256) {
      float cw = cnext;
      if (w < 127) cnext = pbase[(size_t)tid * 8192 + w + 1];  // prefetch
      float sy = 0.f, sz = 0.f;
#pragma unroll
      for (int rr = 0; rr < 8; ++rr) {
        sy += sm.py[rr * 256 + tid];
        sz += sm.pz[rr * 256 + tid];
      }
      float yn = cw + fmaxf(sy, 0.f);
      float zn = yn + fmaxf(sz, 0.f);
      sm.cy[tid] = (_Float16)yn;
      sm.cz[tid] = (_Float16)zn;
      float val = vreg * zn;   // channel dot with conv1 weights (fp32 z)
#pragma unroll
      for (int off = 32; off > 0; off >>= 1) val += __shfl_xor(val, off, 64);
      if (lane == 0) sm.sp[w * 4 + r] = val;
    }
    __syncthreads();
  }

  // s[b,h,127-w] = dot(v, z_w)
  if (tid < 128) {
    float sv = sm.sp[tid * 4 + 0] + sm.sp[tid * 4 + 1] +
               sm.sp[tid * 4 + 2] + sm.sp[tid * 4 + 3];
    sout[(blockIdx.x << 7) + (127 - tid)] = sv;
  }
}

// ---- bilinear 4x upsample (align_corners) of s: (2,64,128) -> (2,256,512) --
static __device__ __forceinline__ float bilin(const float* __restrict__ s,
                                              int idx) {
  int bb  = idx >> 17;          // 131072 outputs per batch
  int rem = idx & 131071;
  int ho  = rem >> 9;           // 0..255
  int wo  = rem & 511;          // 0..511
  const float SY = 63.0f / 255.0f, SX = 127.0f / 511.0f;
  float fy = (float)ho * SY;
  int y0 = (int)fy; int y1 = min(y0 + 1, 63); float wy = fy - (float)y0;
  float fx = (float)wo * SX;
  int x0 = (int)fx; int x1 = min(x0 + 1, 127); float wx = fx - (float)x0;
  const float* sb = s + bb * 8192;
  float cA = sb[y0 * 128 + x0] * (1.f - wy) + sb[y1 * 128 + x0] * wy;
  float cB = sb[y0 * 128 + x1] * (1.f - wy) + sb[y1 * 128 + x1] * wy;
  return cA * (1.f - wx) + cB * wx;
}

// ---- kernel 2: global sum / sumsq of upsampled field -----------------------
extern "C" __global__ void k_stats(const float* __restrict__ s,
                                   float* __restrict__ stats) {
  int tid  = threadIdx.x;
  int base = blockIdx.x * 1024 + tid;
  float sum = 0.f, ssq = 0.f;
#pragma unroll
  for (int i = 0; i < 4; ++i) {
    float u = bilin(s, base + i * 256);
    sum += u; ssq += u * u;
  }
#pragma unroll
  for (int off = 32; off > 0; off >>= 1) {
    sum += __shfl_xor(sum, off, 64);
    ssq += __shfl_xor(ssq, off, 64);
  }
  __shared__ float ls[4], lq[4];
  int wv = tid >> 6;
  if ((tid & 63) == 0) { ls[wv] = sum; lq[wv] = ssq; }
  __syncthreads();
  if (tid == 0) {
    atomicAdd(&stats[0], ls[0] + ls[1] + ls[2] + ls[3]);
    atomicAdd(&stats[1], lq[0] + lq[1] + lq[2] + lq[3]);
  }
}

// ---- kernel 3: normalize + sigmoid -----------------------------------------
extern "C" __global__ void k_norm(const float* __restrict__ s,
                                  const float* __restrict__ stats,
                                  const float* __restrict__ gamma,
                                  const float* __restrict__ beta,
                                  float* __restrict__ out) {
  int tid  = threadIdx.x;
  int base = blockIdx.x * 1024 + tid;
  const float invN = 1.f / 262144.f;
  float mean  = stats[0] * invN;
  float var   = stats[1] * invN - mean * mean;
  float scale = rsqrtf(var + 1e-5f) * gamma[0];
  float bias  = beta[0] - mean * scale;
#pragma unroll
  for (int i = 0; i < 4; ++i) {
    int idx = base + i * 256;
    float u = bilin(s, idx);
    float x = u * scale + bias;
    out[idx] = 1.f / (1.f + __expf(-x));
  }
}

// ---------------------------------------------------------------------------
extern "C" void kernel_launch(void* const* d_in, const int* in_sizes, int n_in,
                              void* d_out, int out_size, void* d_ws, size_t ws_size,
                              hipStream_t stream) {
  const float* p2    = (const float*)d_in[0];   // (2,256,64,128)
  const float* convw = (const float*)d_in[1];   // (256,256,1,9)
  const float* conv1 = (const float*)d_in[2];   // (1,256,1,1)
  const float* gamma = (const float*)d_in[3];   // (1,)
  const float* beta  = (const float*)d_in[4];   // (1,)
  float* out = (float*)d_out;                   // (2,1,256,512) fp32

  char* ws = (char*)d_ws;
  float*    s     = (float*)ws;                 // 16384 floats  [0, 64KB)
  float*    stats = (float*)(ws + 65536);       // 2 floats
  _Float16* Md    = (_Float16*)(ws + 65792);    // 65536 f16 (128 KB)

  hipLaunchKernelGGL(k_extract, dim3(256), dim3(256), 0, stream, convw, Md);
  hipLaunchKernelGGL(k_scan,    dim3(128), dim3(512), 0, stream, p2, Md, conv1, s, stats);
  hipLaunchKernelGGL(k_stats,   dim3(256), dim3(256), 0, stream, s, stats);
  hipLaunchKernelGGL(k_norm,    dim3(256), dim3(256), 0, stream, s, stats, gamma, beta, out);
}

// Round 3
// 201.504 us; speedup vs baseline: 1.0528x; 1.0528x over previous
//
#include <hip/hip_runtime.h>

// ---------------------------------------------------------------------------
// R_SCNN: two width-direction SCNN scans fused into one 127-step recurrence,
// executed with MFMA (K-reduction internal to the instruction, ONE barrier
// per step), 1x1-conv channel-dot folded into the scan, then 4x bilinear
// upsample + global BN + sigmoid on the scalar field.
//
//   y_w = c_w + relu(M y_{w-1}),  z_w = y_w + relu(M z_{w-1}),  z_0 = y_0 = c_0
//   s[b,h,p] = dot(v, z_{127-p});  out = sigmoid(BN(upsample4(s)))
//
// Per step: C[256x2] = M[256x256] * [y z]  via 8 waves x 2 tiles x 8 K-chunks
// of v_mfma_f32_16x16x32_f16. y sits in B column 0, z in column 1; columns
// 2..15 compute redundant copies (column n of B only affects column n of C).
// M is held in registers as A-fragments. Carries are f16 in LDS and
// PING-PONG between two buffers each step: step w reads buf[(w+1)&1] and
// writes buf[w&1], eliminating the cross-wave WAR race that a single shared
// buffer + one barrier would have.
// ---------------------------------------------------------------------------

typedef _Float16 f16x8 __attribute__((ext_vector_type(8)));
typedef _Float16 f16x4 __attribute__((ext_vector_type(4)));
typedef float    f32x4 __attribute__((ext_vector_type(4)));

// ---- kernel 0: extract center tap of conv_w -> dense f16 [o][c], coalesced -
extern "C" __global__ void k_extract(const float* __restrict__ convw,
                                     _Float16* __restrict__ Md) {
  int q = blockIdx.x * 256 + threadIdx.x;   // 147456 float4s = 589824 floats
  float4 v = ((const float4*)convw)[q];
  float vv[4] = {v.x, v.y, v.z, v.w};
  int f = q * 4;
#pragma unroll
  for (int e = 0; e < 4; ++e) {
    int flat = f + e;                       // flat = idx*9 + 4  <=>  center tap
    if (flat % 9 == 4) Md[flat / 9] = (_Float16)vv[e];
  }
}

// ---- kernel 1: fused double scan via MFMA ---------------------------------
struct SM {
  _Float16 cy[2][256];     // y carry (f16), ping-pong
  _Float16 cz[2][256];     // z carry (f16), ping-pong
  float    sp[128 * 32];   // s-dot partials [w][32]
};

extern "C" __global__ void __launch_bounds__(512, 2)
k_scan(const float* __restrict__ p2, const _Float16* __restrict__ Md,
       const float* __restrict__ conv1, float* __restrict__ sout,
       float* __restrict__ stats) {
  __shared__ SM sm;
  const int tid  = threadIdx.x;
  const int l    = tid & 63;
  const int r    = tid >> 6;        // wave 0..7
  const int col  = l & 15;          // MFMA n / A-row-within-tile index
  const int quad = l >> 4;          // MFMA k-group / C-row-group index
  const int b    = blockIdx.x >> 6;
  const int h    = blockIdx.x & 63;

  if (blockIdx.x == 0 && tid == 0) { stats[0] = 0.f; stats[1] = 0.f; }

  const bool isY = (col == 0);      // lanes holding C column 0 (y results)
  const bool isZ = (col == 1);      // lanes holding C column 1 (z results)

  // C/D rows owned by this lane: m0..m0+3 (tile 0), m1..m1+3 (tile 1)
  const int m0 = (r * 2 + 0) * 16 + quad * 4;
  const int m1 = (r * 2 + 1) * 16 + quad * 4;

  // A-fragments (M matrix, resident): lane holds A[m = t*16+col][k = ch*32+quad*8+j]
  f16x8 A0[8], A1[8];
#pragma unroll
  for (int ch = 0; ch < 8; ++ch) {
    A0[ch] = *(const f16x8*)(Md + ((r*2+0)*16 + col) * 256 + ch*32 + quad*8);
    A1[ch] = *(const f16x8*)(Md + ((r*2+1)*16 + col) * 256 + ch*32 + quad*8);
  }

  // p2_r[b][c][h][w]: channel c at pbase + c*8192 + w
  const float* pbase = p2 + (size_t)b * 2097152 + (size_t)h * 128;

  // init: w=0 state (z_0 = y_0 = c_0) into buffer 0, sp[0] partials, v preload
  float vva[4], vvb[4];               // conv1 weights at owned rows (col1 lanes)
  {
    float c0a[4], c0b[4];
    if (isY || isZ) {
#pragma unroll
      for (int i = 0; i < 4; ++i) {
        c0a[i] = pbase[(size_t)(m0 + i) * 8192];
        c0b[i] = pbase[(size_t)(m1 + i) * 8192];
      }
    }
    if (isY) {
      f16x4 pa, pb;
#pragma unroll
      for (int i = 0; i < 4; ++i) { pa[i] = (_Float16)c0a[i]; pb[i] = (_Float16)c0b[i]; }
      *(f16x4*)(sm.cy[0] + m0) = pa; *(f16x4*)(sm.cy[0] + m1) = pb;
      *(f16x4*)(sm.cz[0] + m0) = pa; *(f16x4*)(sm.cz[0] + m1) = pb;
    }
    if (isZ) {
#pragma unroll
      for (int i = 0; i < 4; ++i) { vva[i] = conv1[m0 + i]; vvb[i] = conv1[m1 + i]; }
      float p = 0.f;
#pragma unroll
      for (int i = 0; i < 4; ++i) p += vva[i] * c0a[i] + vvb[i] * c0b[i];
      sm.sp[0 * 32 + r * 4 + quad] = p;
    }
  }

  // c_w prefetch registers (col0 lanes), distance 1
  float ca[4], cb[4];
  if (isY) {
#pragma unroll
    for (int i = 0; i < 4; ++i) {
      ca[i] = pbase[(size_t)(m0 + i) * 8192 + 1];
      cb[i] = pbase[(size_t)(m1 + i) * 8192 + 1];
    }
  }
  __syncthreads();

  // B-fragment source: lane parity picks y (even cols) / z (odd cols).
  const _Float16* selA = ((l & 1) ? sm.cz[0] : sm.cy[0]) + quad * 8;  // read when w odd
  const _Float16* selB = ((l & 1) ? sm.cz[1] : sm.cy[1]) + quad * 8;  // read when w even

  for (int w = 1; w < 128; ++w) {
    // prefetch c for step w+1 (overlaps MFMA phase)
    float na[4], nb[4];
    if (isY && w < 127) {
#pragma unroll
      for (int i = 0; i < 4; ++i) {
        na[i] = pbase[(size_t)(m0 + i) * 8192 + w + 1];
        nb[i] = pbase[(size_t)(m1 + i) * 8192 + w + 1];
      }
    }

    // B-fragments from carries (8 x ds_read_b128, read buffer (w+1)&1)
    const _Float16* sel = (w & 1) ? selA : selB;
    f16x8 B[8];
#pragma unroll
    for (int ch = 0; ch < 8; ++ch)
      B[ch] = *(const f16x8*)(sel + ch * 32);

    f32x4 acc0 = {0.f, 0.f, 0.f, 0.f}, acc1 = {0.f, 0.f, 0.f, 0.f};
#pragma unroll
    for (int ch = 0; ch < 8; ++ch) {
      acc0 = __builtin_amdgcn_mfma_f32_16x16x32_f16(A0[ch], B[ch], acc0, 0, 0, 0);
      acc1 = __builtin_amdgcn_mfma_f32_16x16x32_f16(A1[ch], B[ch], acc1, 0, 0, 0);
    }

    // ---- carry update (write buffer w&1) ----
    _Float16* wy = sm.cy[w & 1];
    _Float16* wz = sm.cz[w & 1];
    // col0 lanes: yn = c_w + relu(sy); write cy
    f16x4 yh0 = {}, yh1 = {};
    if (isY) {
#pragma unroll
      for (int i = 0; i < 4; ++i) {
        yh0[i] = (_Float16)(ca[i] + fmaxf(acc0[i], 0.f));
        yh1[i] = (_Float16)(cb[i] + fmaxf(acc1[i], 0.f));
      }
      *(f16x4*)(wy + m0) = yh0;
      *(f16x4*)(wy + m1) = yh1;
    }
    // broadcast packed yn from the even (col0) lane of each pair
    int2 u0 = __builtin_bit_cast(int2, yh0), u1 = __builtin_bit_cast(int2, yh1);
    u0.x = __shfl(u0.x, l & 62, 64); u0.y = __shfl(u0.y, l & 62, 64);
    u1.x = __shfl(u1.x, l & 62, 64); u1.y = __shfl(u1.y, l & 62, 64);
    f16x4 ys0 = __builtin_bit_cast(f16x4, u0), ys1 = __builtin_bit_cast(f16x4, u1);
    // col1 lanes: zn = yn + relu(sz); write cz; accumulate s-dot partial
    if (isZ) {
      f16x4 zh0, zh1;
      float p = 0.f;
#pragma unroll
      for (int i = 0; i < 4; ++i) {
        float z0 = (float)ys0[i] + fmaxf(acc0[i], 0.f);
        float z1 = (float)ys1[i] + fmaxf(acc1[i], 0.f);
        zh0[i] = (_Float16)z0; zh1[i] = (_Float16)z1;
        p += vva[i] * z0 + vvb[i] * z1;
      }
      *(f16x4*)(wz + m0) = zh0;
      *(f16x4*)(wz + m1) = zh1;
      sm.sp[w * 32 + r * 4 + quad] = p;
    }
    if (isY) {
#pragma unroll
      for (int i = 0; i < 4; ++i) { ca[i] = na[i]; cb[i] = nb[i]; }
    }
    __syncthreads();
  }

  // s[b,h,127-w] = dot(v, z_w): reduce the 32 partials per step
  if (tid < 128) {
    const float4* q = (const float4*)(sm.sp + tid * 32);
    float s = 0.f;
#pragma unroll
    for (int j = 0; j < 8; ++j) { float4 t4 = q[j]; s += t4.x + t4.y + t4.z + t4.w; }
    sout[(blockIdx.x << 7) + (127 - tid)] = s;
  }
}

// ---- bilinear 4x upsample (align_corners) of s: (2,64,128) -> (2,256,512) --
static __device__ __forceinline__ float bilin(const float* __restrict__ s,
                                              int idx) {
  int bb  = idx >> 17;
  int rem = idx & 131071;
  int ho  = rem >> 9;
  int wo  = rem & 511;
  const float SY = 63.0f / 255.0f, SX = 127.0f / 511.0f;
  float fy = (float)ho * SY;
  int y0 = (int)fy; int y1 = min(y0 + 1, 63); float wy = fy - (float)y0;
  float fx = (float)wo * SX;
  int x0 = (int)fx; int x1 = min(x0 + 1, 127); float wx = fx - (float)x0;
  const float* sb = s + bb * 8192;
  float cA = sb[y0 * 128 + x0] * (1.f - wy) + sb[y1 * 128 + x0] * wy;
  float cB = sb[y0 * 128 + x1] * (1.f - wy) + sb[y1 * 128 + x1] * wy;
  return cA * (1.f - wx) + cB * wx;
}

// ---- kernel 2: global sum / sumsq of upsampled field -----------------------
extern "C" __global__ void k_stats(const float* __restrict__ s,
                                   float* __restrict__ stats) {
  int tid  = threadIdx.x;
  int base = blockIdx.x * 1024 + tid;
  float sum = 0.f, ssq = 0.f;
#pragma unroll
  for (int i = 0; i < 4; ++i) {
    float u = bilin(s, base + i * 256);
    sum += u; ssq += u * u;
  }
#pragma unroll
  for (int off = 32; off > 0; off >>= 1) {
    sum += __shfl_xor(sum, off, 64);
    ssq += __shfl_xor(ssq, off, 64);
  }
  __shared__ float ls[4], lq[4];
  int wv = tid >> 6;
  if ((tid & 63) == 0) { ls[wv] = sum; lq[wv] = ssq; }
  __syncthreads();
  if (tid == 0) {
    atomicAdd(&stats[0], ls[0] + ls[1] + ls[2] + ls[3]);
    atomicAdd(&stats[1], lq[0] + lq[1] + lq[2] + lq[3]);
  }
}

// ---- kernel 3: normalize + sigmoid -----------------------------------------
extern "C" __global__ void k_norm(const float* __restrict__ s,
                                  const float* __restrict__ stats,
                                  const float* __restrict__ gamma,
                                  const float* __restrict__ beta,
                                  float* __restrict__ out) {
  int tid  = threadIdx.x;
  int base = blockIdx.x * 1024 + tid;
  const float invN = 1.f / 262144.f;
  float mean  = stats[0] * invN;
  float var   = stats[1] * invN - mean * mean;
  float scale = rsqrtf(var + 1e-5f) * gamma[0];
  float bias  = beta[0] - mean * scale;
#pragma unroll
  for (int i = 0; i < 4; ++i) {
    int idx = base + i * 256;
    float u = bilin(s, idx);
    float x = u * scale + bias;
    out[idx] = 1.f / (1.f + __expf(-x));
  }
}

// ---------------------------------------------------------------------------
extern "C" void kernel_launch(void* const* d_in, const int* in_sizes, int n_in,
                              void* d_out, int out_size, void* d_ws, size_t ws_size,
                              hipStream_t stream) {
  const float* p2    = (const float*)d_in[0];   // (2,256,64,128)
  const float* convw = (const float*)d_in[1];   // (256,256,1,9)
  const float* conv1 = (const float*)d_in[2];   // (1,256,1,1)
  const float* gamma = (const float*)d_in[3];   // (1,)
  const float* beta  = (const float*)d_in[4];   // (1,)
  float* out = (float*)d_out;                   // (2,1,256,512) fp32

  char* ws = (char*)d_ws;
  float*    s     = (float*)ws;                 // 16384 floats  [0, 64KB)
  float*    stats = (float*)(ws + 65536);       // 2 floats
  _Float16* Md    = (_Float16*)(ws + 65792);    // 65536 f16 (128 KB)

  hipLaunchKernelGGL(k_extract, dim3(576), dim3(256), 0, stream, convw, Md);
  hipLaunchKernelGGL(k_scan,    dim3(128), dim3(512), 0, stream, p2, Md, conv1, s, stats);
  hipLaunchKernelGGL(k_stats,   dim3(256), dim3(256), 0, stream, s, stats);
  hipLaunchKernelGGL(k_norm,    dim3(256), dim3(256), 0, stream, s, stats, gamma, beta, out);
}

// Round 4
// 184.783 us; speedup vs baseline: 1.1481x; 1.0905x over previous
//
#include <hip/hip_runtime.h>

// ---------------------------------------------------------------------------
// R_SCNN: two width-direction SCNN scans fused into one 127-step recurrence,
// executed with MFMA, ONE barrier per step, 1x1-conv channel-dot folded into
// the scan, then 4x bilinear upsample + global BN + sigmoid.
//
//   y_w = c_w + relu(M y_{w-1}),  z_w = y_w + relu(M z_{w-1}),  z_0 = y_0 = c_0
//   s[b,h,p] = dot(v, z_{127-p});  out = sigmoid(BN(upsample4(s)))
//
// Round-4 path work: (1) 2-step unroll with a depth-2 c_w register pipeline
// (loads have ~2 steps in flight -> HBM-miss latency off the path, no rotate
// movs, static ping-pong buffer select); (2) 64B pad between cy and cz so y-
// and z-lane B-reads hit disjoint LDS bank halves (R3 measured 4.2M conflict
// cycles); (3) MFMA K-chain split into 4 independent chains of 4 (+2 vector
// adds) to cut the dependent-latency tail.
// ---------------------------------------------------------------------------

typedef _Float16 f16x8 __attribute__((ext_vector_type(8)));
typedef _Float16 f16x4 __attribute__((ext_vector_type(4)));
typedef float    f32x4 __attribute__((ext_vector_type(4)));

// ---- kernel 0: extract center tap of conv_w -> dense f16 [o][c], coalesced -
extern "C" __global__ void k_extract(const float* __restrict__ convw,
                                     _Float16* __restrict__ Md) {
  int q = blockIdx.x * 256 + threadIdx.x;   // 147456 float4s = 589824 floats
  float4 v = ((const float4*)convw)[q];
  float vv[4] = {v.x, v.y, v.z, v.w};
  int f = q * 4;
#pragma unroll
  for (int e = 0; e < 4; ++e) {
    int flat = f + e;                       // flat = idx*9 + 4  <=>  center tap
    if (flat % 9 == 4) Md[flat / 9] = (_Float16)vv[e];
  }
}

// ---- kernel 1: fused double scan via MFMA ---------------------------------
struct SM {
  _Float16 cy[2][256];     // y carry (f16), ping-pong           [byte 0)
  _Float16 pad_[32];       // 64B: shifts cz banks by 16 vs cy
  _Float16 cz[2][256];     // z carry (f16), ping-pong           [byte 1088)
  float    sp[128 * 32];   // s-dot partials [w][32]
};

extern "C" __global__ void __launch_bounds__(512, 2)
k_scan(const float* __restrict__ p2, const _Float16* __restrict__ Md,
       const float* __restrict__ conv1, float* __restrict__ sout,
       float* __restrict__ stats) {
  __shared__ SM sm;
  const int tid  = threadIdx.x;
  const int l    = tid & 63;
  const int r    = tid >> 6;        // wave 0..7
  const int col  = l & 15;          // MFMA n / A-row-within-tile index
  const int quad = l >> 4;          // MFMA k-group / C-row-group index
  const int b    = blockIdx.x >> 6;
  const int h    = blockIdx.x & 63;

  if (blockIdx.x == 0 && tid == 0) { stats[0] = 0.f; stats[1] = 0.f; }

  const bool isY = (col == 0);      // lanes holding C column 0 (y results)
  const bool isZ = (col == 1);      // lanes holding C column 1 (z results)

  // C/D rows owned by this lane: m0..m0+3 (tile 0), m1..m1+3 (tile 1)
  const int m0 = (r * 2 + 0) * 16 + quad * 4;
  const int m1 = (r * 2 + 1) * 16 + quad * 4;

  // A-fragments (M matrix, resident): lane holds A[m = t*16+col][k = ch*32+quad*8+j]
  f16x8 A0[8], A1[8];
#pragma unroll
  for (int ch = 0; ch < 8; ++ch) {
    A0[ch] = *(const f16x8*)(Md + ((r*2+0)*16 + col) * 256 + ch*32 + quad*8);
    A1[ch] = *(const f16x8*)(Md + ((r*2+1)*16 + col) * 256 + ch*32 + quad*8);
  }

  // p2_r[b][c][h][w]: channel c at pbase + c*8192 + w
  const float* pbase = p2 + (size_t)b * 2097152 + (size_t)h * 128;

  // init: w=0 state (z_0 = y_0 = c_0) into buffer 0, sp[0] partials, v preload
  float vva[4], vvb[4];               // conv1 weights at owned rows (col1 lanes)
  {
    float c0a[4], c0b[4];
    if (isY || isZ) {
#pragma unroll
      for (int i = 0; i < 4; ++i) {
        c0a[i] = pbase[(size_t)(m0 + i) * 8192];
        c0b[i] = pbase[(size_t)(m1 + i) * 8192];
      }
    }
    if (isY) {
      f16x4 pa, pb;
#pragma unroll
      for (int i = 0; i < 4; ++i) { pa[i] = (_Float16)c0a[i]; pb[i] = (_Float16)c0b[i]; }
      *(f16x4*)(sm.cy[0] + m0) = pa; *(f16x4*)(sm.cy[0] + m1) = pb;
      *(f16x4*)(sm.cz[0] + m0) = pa; *(f16x4*)(sm.cz[0] + m1) = pb;
    }
    if (isZ) {
#pragma unroll
      for (int i = 0; i < 4; ++i) { vva[i] = conv1[m0 + i]; vvb[i] = conv1[m1 + i]; }
      float p = 0.f;
#pragma unroll
      for (int i = 0; i < 4; ++i) p += vva[i] * c0a[i] + vvb[i] * c0b[i];
      sm.sp[0 * 32 + r * 4 + quad] = p;
    }
  }

  // depth-2 c_w pipeline (isY lanes): cca/ccb = c_w for odd steps,
  // cna/cnb = c_w for even steps; each half reloads its own set for w+2.
  float cca[4], ccb[4], cna[4], cnb[4];
  if (isY) {
#pragma unroll
    for (int i = 0; i < 4; ++i) {
      cca[i] = pbase[(size_t)(m0 + i) * 8192 + 1];
      ccb[i] = pbase[(size_t)(m1 + i) * 8192 + 1];
      cna[i] = pbase[(size_t)(m0 + i) * 8192 + 2];
      cnb[i] = pbase[(size_t)(m1 + i) * 8192 + 2];
    }
  }
  __syncthreads();

  // B-fragment source: lane parity picks y (even cols) / z (odd cols).
  const _Float16* selA = ((l & 1) ? sm.cz[0] : sm.cy[0]) + quad * 8;  // read when w odd
  const _Float16* selB = ((l & 1) ? sm.cz[1] : sm.cy[1]) + quad * 8;  // read when w even

#define STEP(W, SELP, WY, WZ, CA, CB)                                          \
  do {                                                                         \
    f16x8 B[8];                                                                \
    _Pragma("unroll")                                                          \
    for (int ch = 0; ch < 8; ++ch)                                             \
      B[ch] = *(const f16x8*)((SELP) + ch * 32);                               \
    f32x4 a00 = {0.f,0.f,0.f,0.f}, a01 = {0.f,0.f,0.f,0.f};                    \
    f32x4 a10 = {0.f,0.f,0.f,0.f}, a11 = {0.f,0.f,0.f,0.f};                    \
    _Pragma("unroll")                                                          \
    for (int ch = 0; ch < 4; ++ch) {                                           \
      a00 = __builtin_amdgcn_mfma_f32_16x16x32_f16(A0[ch],   B[ch],   a00,0,0,0);\
      a10 = __builtin_amdgcn_mfma_f32_16x16x32_f16(A1[ch],   B[ch],   a10,0,0,0);\
      a01 = __builtin_amdgcn_mfma_f32_16x16x32_f16(A0[ch+4], B[ch+4], a01,0,0,0);\
      a11 = __builtin_amdgcn_mfma_f32_16x16x32_f16(A1[ch+4], B[ch+4], a11,0,0,0);\
    }                                                                          \
    f32x4 acc0 = a00 + a01, acc1 = a10 + a11;                                  \
    f16x4 yh0 = {}, yh1 = {};                                                  \
    if (isY) {                                                                 \
      _Pragma("unroll")                                                        \
      for (int i = 0; i < 4; ++i) {                                            \
        yh0[i] = (_Float16)((CA)[i] + fmaxf(acc0[i], 0.f));                    \
        yh1[i] = (_Float16)((CB)[i] + fmaxf(acc1[i], 0.f));                    \
      }                                                                        \
      *(f16x4*)((WY) + m0) = yh0;                                              \
      *(f16x4*)((WY) + m1) = yh1;                                              \
      if ((W) + 2 < 128) {                                                     \
        _Pragma("unroll")                                                      \
        for (int i = 0; i < 4; ++i) {                                          \
          (CA)[i] = pbase[(size_t)(m0 + i) * 8192 + (W) + 2];                  \
          (CB)[i] = pbase[(size_t)(m1 + i) * 8192 + (W) + 2];                  \
        }                                                                      \
      }                                                                        \
    }                                                                          \
    int2 u0 = __builtin_bit_cast(int2, yh0), u1 = __builtin_bit_cast(int2, yh1);\
    u0.x = __shfl(u0.x, l & 62, 64); u0.y = __shfl(u0.y, l & 62, 64);          \
    u1.x = __shfl(u1.x, l & 62, 64); u1.y = __shfl(u1.y, l & 62, 64);          \
    f16x4 ys0 = __builtin_bit_cast(f16x4, u0), ys1 = __builtin_bit_cast(f16x4, u1);\
    if (isZ) {                                                                 \
      f16x4 zh0, zh1;                                                          \
      float p = 0.f;                                                           \
      _Pragma("unroll")                                                        \
      for (int i = 0; i < 4; ++i) {                                            \
        float z0 = (float)ys0[i] + fmaxf(acc0[i], 0.f);                        \
        float z1 = (float)ys1[i] + fmaxf(acc1[i], 0.f);                        \
        zh0[i] = (_Float16)z0; zh1[i] = (_Float16)z1;                          \
        p += vva[i] * z0 + vvb[i] * z1;                                        \
      }                                                                        \
      *(f16x4*)((WZ) + m0) = zh0;                                              \
      *(f16x4*)((WZ) + m1) = zh1;                                              \
      sm.sp[(W) * 32 + r * 4 + quad] = p;                                      \
    }                                                                          \
    __syncthreads();                                                           \
  } while (0)

#pragma unroll 1
  for (int w = 1; w < 127; w += 2) {
    STEP(w,     selA, sm.cy[1], sm.cz[1], cca, ccb);  // read buf0, write buf1
    STEP(w + 1, selB, sm.cy[0], sm.cz[0], cna, cnb);  // read buf1, write buf0
  }
  STEP(127, selA, sm.cy[1], sm.cz[1], cca, ccb);
#undef STEP

  // s[b,h,127-w] = dot(v, z_w): reduce the 32 partials per step
  if (tid < 128) {
    const float4* q = (const float4*)(sm.sp + tid * 32);
    float s = 0.f;
#pragma unroll
    for (int j = 0; j < 8; ++j) { float4 t4 = q[j]; s += t4.x + t4.y + t4.z + t4.w; }
    sout[(blockIdx.x << 7) + (127 - tid)] = s;
  }
}

// ---- bilinear 4x upsample (align_corners) of s: (2,64,128) -> (2,256,512) --
static __device__ __forceinline__ float bilin(const float* __restrict__ s,
                                              int idx) {
  int bb  = idx >> 17;
  int rem = idx & 131071;
  int ho  = rem >> 9;
  int wo  = rem & 511;
  const float SY = 63.0f / 255.0f, SX = 127.0f / 511.0f;
  float fy = (float)ho * SY;
  int y0 = (int)fy; int y1 = min(y0 + 1, 63); float wy = fy - (float)y0;
  float fx = (float)wo * SX;
  int x0 = (int)fx; int x1 = min(x0 + 1, 127); float wx = fx - (float)x0;
  const float* sb = s + bb * 8192;
  float cA = sb[y0 * 128 + x0] * (1.f - wy) + sb[y1 * 128 + x0] * wy;
  float cB = sb[y0 * 128 + x1] * (1.f - wy) + sb[y1 * 128 + x1] * wy;
  return cA * (1.f - wx) + cB * wx;
}

// ---- kernel 2: global sum / sumsq of upsampled field -----------------------
extern "C" __global__ void k_stats(const float* __restrict__ s,
                                   float* __restrict__ stats) {
  int tid  = threadIdx.x;
  int base = blockIdx.x * 1024 + tid;
  float sum = 0.f, ssq = 0.f;
#pragma unroll
  for (int i = 0; i < 4; ++i) {
    float u = bilin(s, base + i * 256);
    sum += u; ssq += u * u;
  }
#pragma unroll
  for (int off = 32; off > 0; off >>= 1) {
    sum += __shfl_xor(sum, off, 64);
    ssq += __shfl_xor(ssq, off, 64);
  }
  __shared__ float ls[4], lq[4];
  int wv = tid >> 6;
  if ((tid & 63) == 0) { ls[wv] = sum; lq[wv] = ssq; }
  __syncthreads();
  if (tid == 0) {
    atomicAdd(&stats[0], ls[0] + ls[1] + ls[2] + ls[3]);
    atomicAdd(&stats[1], lq[0] + lq[1] + lq[2] + lq[3]);
  }
}

// ---- kernel 3: normalize + sigmoid -----------------------------------------
extern "C" __global__ void k_norm(const float* __restrict__ s,
                                  const float* __restrict__ stats,
                                  const float* __restrict__ gamma,
                                  const float* __restrict__ beta,
                                  float* __restrict__ out) {
  int tid  = threadIdx.x;
  int base = blockIdx.x * 1024 + tid;
  const float invN = 1.f / 262144.f;
  float mean  = stats[0] * invN;
  float var   = stats[1] * invN - mean * mean;
  float scale = rsqrtf(var + 1e-5f) * gamma[0];
  float bias  = beta[0] - mean * scale;
#pragma unroll
  for (int i = 0; i < 4; ++i) {
    int idx = base + i * 256;
    float u = bilin(s, idx);
    float x = u * scale + bias;
    out[idx] = 1.f / (1.f + __expf(-x));
  }
}

// ---------------------------------------------------------------------------
extern "C" void kernel_launch(void* const* d_in, const int* in_sizes, int n_in,
                              void* d_out, int out_size, void* d_ws, size_t ws_size,
                              hipStream_t stream) {
  const float* p2    = (const float*)d_in[0];   // (2,256,64,128)
  const float* convw = (const float*)d_in[1];   // (256,256,1,9)
  const float* conv1 = (const float*)d_in[2];   // (1,256,1,1)
  const float* gamma = (const float*)d_in[3];   // (1,)
  const float* beta  = (const float*)d_in[4];   // (1,)
  float* out = (float*)d_out;                   // (2,1,256,512) fp32

  char* ws = (char*)d_ws;
  float*    s     = (float*)ws;                 // 16384 floats  [0, 64KB)
  float*    stats = (float*)(ws + 65536);       // 2 floats
  _Float16* Md    = (_Float16*)(ws + 65792);    // 65536 f16 (128 KB)

  hipLaunchKernelGGL(k_extract, dim3(576), dim3(256), 0, stream, convw, Md);
  hipLaunchKernelGGL(k_scan,    dim3(128), dim3(512), 0, stream, p2, Md, conv1, s, stats);
  hipLaunchKernelGGL(k_stats,   dim3(256), dim3(256), 0, stream, s, stats);
  hipLaunchKernelGGL(k_norm,    dim3(256), dim3(256), 0, stream, s, stats, gamma, beta, out);
}